// Round 6
// baseline (1030.964 us; speedup 1.0000x reference)
//
#include <hip/hip_runtime.h>
#include <cstdint>

#define F_IN 256
#define F_H  16
#define F_C  40

// ---------------------------------------------------------------------------
// K1: t1[N,16] = x[N,256] @ W1[256,16]
// ---------------------------------------------------------------------------
__global__ __launch_bounds__(256) void gemm1_kernel(
    const float* __restrict__ x, const float* __restrict__ W1,
    float* __restrict__ t1, int N) {
  __shared__ float wlds[F_IN * F_H];   // layout [k][f]
  __shared__ float xlds[16 * 260];     // 16 rows, padded stride 260
  const int tid = threadIdx.x;
  const int nodeBase = blockIdx.x * 16;

  for (int i = tid; i < F_IN * F_H; i += 256) wlds[i] = W1[i];

  const float4* x4 = reinterpret_cast<const float4*>(x) + (size_t)nodeBase * (F_IN / 4);
  for (int i = tid; i < 16 * (F_IN / 4); i += 256) {
    int r = i >> 6;
    int c4 = i & 63;
    float4 v = make_float4(0.f, 0.f, 0.f, 0.f);
    if (nodeBase + r < N) v = x4[(size_t)r * (F_IN / 4) + c4];
    *reinterpret_cast<float4*>(&xlds[r * 260 + c4 * 4]) = v;
  }
  __syncthreads();

  const int r = tid >> 4;
  const int f = tid & 15;
  const float* xr = &xlds[r * 260];
  float acc = 0.f;
#pragma unroll 8
  for (int k = 0; k < F_IN; ++k) acc = fmaf(xr[k], wlds[k * F_H + f], acc);
  if (nodeBase + r < N) t1[(size_t)nodeBase * F_H + tid] = acc;
}

// ---------------------------------------------------------------------------
// CSR build step A: histogram of dst into cnt (aliased with cursor)
// ---------------------------------------------------------------------------
__global__ __launch_bounds__(256) void hist_kernel(
    const int* __restrict__ ei, int* __restrict__ cnt, int N, int E) {
  int e = blockIdx.x * 256 + threadIdx.x;
  if (e >= E) return;
  int d = ei[E + e];
  if ((unsigned)d >= (unsigned)N) return;
  atomicAdd(&cnt[d], 1);
}

// ---------------------------------------------------------------------------
// CSR build step B: single-block exclusive scan. cnt aliases cursor (in-place):
// reads cnt[i], writes rowptr[i] and cursor[i] = exclusive prefix.
// ---------------------------------------------------------------------------
__global__ __launch_bounds__(1024) void scan_kernel(
    int* __restrict__ cnt_cursor, int* __restrict__ rowptr, int N) {
  __shared__ int part[1024];
  const int t = threadIdx.x;
  const int C = (N + 1023) / 1024;
  const int beg = t * C;
  const int end = min(beg + C, N);

  int s = 0;
  for (int i = beg; i < end; ++i) s += cnt_cursor[i];
  part[t] = s;
  __syncthreads();
  // Hillis-Steele inclusive scan over the 1024 partials
  for (int off = 1; off < 1024; off <<= 1) {
    int v = (t >= off) ? part[t - off] : 0;
    __syncthreads();
    if (t >= off) part[t] += v;
    __syncthreads();
  }
  int prefix = (t == 0) ? 0 : part[t - 1];
  for (int i = beg; i < end; ++i) {
    int c = cnt_cursor[i];        // read BEFORE overwrite (aliased)
    rowptr[i] = prefix;
    cnt_cursor[i] = prefix;       // cursor for the permute pass
    prefix += c;
  }
  if (t == 1023) rowptr[N] = part[1023];
}

// ---------------------------------------------------------------------------
// CSR build step C: permute edges into dst-sorted order. srcw[pos] = {src, w}
// ---------------------------------------------------------------------------
__global__ __launch_bounds__(256) void permute_kernel(
    const int* __restrict__ ei, const float* __restrict__ ew,
    int* __restrict__ cursor, int2* __restrict__ srcw, int N, int E) {
  int e = blockIdx.x * 256 + threadIdx.x;
  if (e >= E) return;
  int s = ei[e];
  int d = ei[E + e];
  if ((unsigned)s >= (unsigned)N || (unsigned)d >= (unsigned)N) return;
  int pos = atomicAdd(&cursor[d], 1);
  srcw[pos] = make_int2(s, __float_as_int(ew[e]));
}

// ---------------------------------------------------------------------------
// K2: gather-aggregate layer1 — agg1[n,f] = sum_{e: dst=n} t1[src,f]*w
// 256 thr = 16 nodes x 16 feats. srcw[j] broadcast within 16-lane group;
// t1 row read is one contiguous 64B line. No atomics.
// ---------------------------------------------------------------------------
__global__ __launch_bounds__(256) void agg1_kernel(
    const float* __restrict__ t1, const int2* __restrict__ srcw,
    const int* __restrict__ rowptr, float* __restrict__ agg1, int N) {
  const int tid = threadIdx.x;
  const int node = blockIdx.x * 16 + (tid >> 4);
  const int f = tid & 15;
  if (node >= N) return;
  const int beg = rowptr[node];
  const int end = rowptr[node + 1];
  float acc = 0.f;
  for (int j = beg; j < end; ++j) {
    int2 sw = srcw[j];
    acc = fmaf(t1[(size_t)sw.x * F_H + f], __int_as_float(sw.y), acc);
  }
  agg1[(size_t)node * F_H + f] = acc;
}

// ---------------------------------------------------------------------------
// K3: gather-aggregate layer2 in hidden space (W2 applied after):
//   agg2[n,f] = sum_{e: dst=n} relu(agg1[src,f] + b1[f]) * w
// ---------------------------------------------------------------------------
__global__ __launch_bounds__(256) void agg2_kernel(
    const float* __restrict__ agg1, const float* __restrict__ b1,
    const int2* __restrict__ srcw, const int* __restrict__ rowptr,
    float* __restrict__ agg2, int N) {
  const int tid = threadIdx.x;
  const int node = blockIdx.x * 16 + (tid >> 4);
  const int f = tid & 15;
  if (node >= N) return;
  const float bf = b1[f];
  const int beg = rowptr[node];
  const int end = rowptr[node + 1];
  float acc = 0.f;
  for (int j = beg; j < end; ++j) {
    int2 sw = srcw[j];
    float v = agg1[(size_t)sw.x * F_H + f] + bf;
    v = v > 0.f ? v : 0.f;
    acc = fmaf(v, __int_as_float(sw.y), acc);
  }
  agg2[(size_t)node * F_H + f] = acc;
}

// ---------------------------------------------------------------------------
// K4: fused epilogue — out[n] = log_softmax(agg2[n] @ W2 + b2)
// ---------------------------------------------------------------------------
__global__ __launch_bounds__(320) void gemm2_lsm_kernel(
    const float* __restrict__ agg2, const float* __restrict__ W2,
    const float* __restrict__ b2, float* __restrict__ out, int N) {
  __shared__ float w2lds[F_H * F_C];
  __shared__ float alds[8 * F_H];
  __shared__ float slds[8 * F_C];
  __shared__ float mlog[8];
  const int tid = threadIdx.x;
  const int nodeBase = blockIdx.x * 8;

  for (int i = tid; i < F_H * F_C; i += 320) w2lds[i] = W2[i];
  if (tid < 8 * F_H) {
    int node = nodeBase + (tid >> 4);
    alds[tid] = (node < N) ? agg2[(size_t)nodeBase * F_H + tid] : 0.f;
  }
  __syncthreads();

  const int ln = tid / F_C;
  const int c = tid - ln * F_C;
  float acc = b2[c];
#pragma unroll
  for (int k = 0; k < F_H; ++k) acc = fmaf(alds[ln * F_H + k], w2lds[k * F_C + c], acc);
  slds[tid] = acc;
  __syncthreads();

  if (tid < 8) {
    const float* row = &slds[tid * F_C];
    float m = -INFINITY;
#pragma unroll
    for (int f = 0; f < F_C; ++f) m = fmaxf(m, row[f]);
    float s = 0.f;
#pragma unroll
    for (int f = 0; f < F_C; ++f) s += expf(row[f] - m);
    mlog[tid] = m + logf(s);
  }
  __syncthreads();

  const int node = nodeBase + ln;
  if (node < N) out[(size_t)nodeBase * F_C + tid] = slds[tid] - mlog[ln];
}

// ---------------------------------------------------------------------------
// Fallback atomic scatters (used only if ws_size too small for CSR buffers)
// ---------------------------------------------------------------------------
__global__ __launch_bounds__(256) void scatter1_kernel(
    const float* __restrict__ t1, const int* __restrict__ ei,
    const float* __restrict__ ew, float* __restrict__ agg1, int N, int E) {
  int gid = blockIdx.x * 256 + threadIdx.x;
  int e = gid >> 4;
  int f = gid & 15;
  if (e >= E) return;
  int s = ei[e];
  int d = ei[E + e];
  if ((unsigned)s >= (unsigned)N || (unsigned)d >= (unsigned)N) return;
  unsafeAtomicAdd(&agg1[(size_t)d * F_H + f], t1[(size_t)s * F_H + f] * ew[e]);
}

__global__ __launch_bounds__(256) void scatter2_kernel(
    const float* __restrict__ agg1, const float* __restrict__ b1,
    const int* __restrict__ ei, const float* __restrict__ ew,
    float* __restrict__ agg2, int N, int E) {
  int gid = blockIdx.x * 256 + threadIdx.x;
  int e = gid >> 4;
  int f = gid & 15;
  if (e >= E) return;
  int s = ei[e];
  int d = ei[E + e];
  if ((unsigned)s >= (unsigned)N || (unsigned)d >= (unsigned)N) return;
  float v = agg1[(size_t)s * F_H + f] + b1[f];
  v = v > 0.f ? v : 0.f;
  unsafeAtomicAdd(&agg2[(size_t)d * F_H + f], v * ew[e]);
}

// ---------------------------------------------------------------------------
extern "C" void kernel_launch(void* const* d_in, const int* in_sizes, int n_in,
                              void* d_out, int out_size, void* d_ws, size_t ws_size,
                              hipStream_t stream) {
  const float* x  = (const float*)d_in[0];
  const int*   ei = (const int*)d_in[1];
  const float* ew = (const float*)d_in[2];
  const float* W1 = (const float*)d_in[3];
  const float* b1 = (const float*)d_in[4];
  const float* W2 = (const float*)d_in[5];
  const float* b2 = (const float*)d_in[6];
  float* out = (float*)d_out;

  const int N = in_sizes[0] / F_IN;
  const int E = in_sizes[2];

  // ws layout: t1[N*16] f32 | agg1[N*16] f32 | agg2[N*16] f32 |
  //            rowptr[N+1] i32 | cursor[N] i32 | srcw[E] int2
  float* t1     = (float*)d_ws;
  float* agg1   = t1 + (size_t)N * F_H;
  float* agg2   = agg1 + (size_t)N * F_H;
  int*   rowptr = (int*)(agg2 + (size_t)N * F_H);
  int*   cursor = rowptr + (N + 1);
  int2*  srcw   = (int2*)(cursor + N);
  size_t needed = (size_t)((char*)(srcw + E) - (char*)d_ws);

  gemm1_kernel<<<(N + 15) / 16, 256, 0, stream>>>(x, W1, t1, N);

  if (ws_size >= needed) {
    // --- CSR gather path: build dst-sorted edge list once, no atomics in agg
    hipMemsetAsync(cursor, 0, (size_t)N * sizeof(int), stream);
    hist_kernel<<<(E + 255) / 256, 256, 0, stream>>>(ei, cursor, N, E);
    scan_kernel<<<1, 1024, 0, stream>>>(cursor, rowptr, N);
    permute_kernel<<<(E + 255) / 256, 256, 0, stream>>>(ei, ew, cursor, srcw, N, E);
    agg1_kernel<<<(N + 15) / 16, 256, 0, stream>>>(t1, srcw, rowptr, agg1, N);
    agg2_kernel<<<(N + 15) / 16, 256, 0, stream>>>(agg1, b1, srcw, rowptr, agg2, N);
  } else {
    // --- fallback: atomic scatters
    hipMemsetAsync(agg1, 0, (size_t)N * F_H * 2 * sizeof(float), stream);
    scatter1_kernel<<<((size_t)E * 16 + 255) / 256, 256, 0, stream>>>(t1, ei, ew, agg1, N, E);
    scatter2_kernel<<<((size_t)E * 16 + 255) / 256, 256, 0, stream>>>(agg1, b1, ei, ew, agg2, N, E);
  }

  gemm2_lsm_kernel<<<(N + 7) / 8, 320, 0, stream>>>(agg2, W2, b2, out, N);
}

// Round 7
// 552.927 us; speedup vs baseline: 1.8646x; 1.8646x over previous
//
#include <hip/hip_runtime.h>
#include <hip/hip_bf16.h>
#include <cstdint>

#define F_IN 256
#define F_H  16
#define F_P  8    // bf16 pairs per hidden row
#define F_C  40

// ---------------------------------------------------------------------------
// K1: t1[N,16] = x[N,256] @ W1[256,16], stored as bf16 PAIRS (__hip_bfloat162)
// block = 256 threads, 16 nodes per block. W1 + x-tile staged in LDS.
// ---------------------------------------------------------------------------
__global__ __launch_bounds__(256) void gemm1_kernel(
    const float* __restrict__ x, const float* __restrict__ W1,
    __hip_bfloat162* __restrict__ t1, int N) {
  __shared__ float wlds[F_IN * F_H];   // layout [k][f]
  __shared__ float xlds[16 * 260];     // 16 rows, padded stride 260
  const int tid = threadIdx.x;
  const int nodeBase = blockIdx.x * 16;

  for (int i = tid; i < F_IN * F_H; i += 256) wlds[i] = W1[i];

  const float4* x4 = reinterpret_cast<const float4*>(x) + (size_t)nodeBase * (F_IN / 4);
  for (int i = tid; i < 16 * (F_IN / 4); i += 256) {
    int r = i >> 6;
    int c4 = i & 63;
    float4 v = make_float4(0.f, 0.f, 0.f, 0.f);
    if (nodeBase + r < N) v = x4[(size_t)r * (F_IN / 4) + c4];
    *reinterpret_cast<float4*>(&xlds[r * 260 + c4 * 4]) = v;
  }
  __syncthreads();

  const int r = tid >> 4;      // node within tile
  const int f = tid & 15;      // output feature
  const float* xr = &xlds[r * 260];
  float acc = 0.f;
#pragma unroll 8
  for (int k = 0; k < F_IN; ++k) acc = fmaf(xr[k], wlds[k * F_H + f], acc);

  // pack pairs: even lane takes partner's value via shfl
  float hi = __shfl_down(acc, 1);
  if (((f & 1) == 0) && (nodeBase + r < N)) {
    __hip_bfloat162 h2 = __halves2bfloat162(__float2bfloat16(acc), __float2bfloat16(hi));
    t1[(size_t)(nodeBase + r) * F_P + (f >> 1)] = h2;
  }
}

// ---------------------------------------------------------------------------
// K2: scatter layer1 — agg1[dst] += t1[src] * w, packed-bf16 atomics.
// thread = (edge, pair); 8 consecutive threads share one edge.
// ---------------------------------------------------------------------------
__global__ __launch_bounds__(256) void scatter1_kernel(
    const __hip_bfloat162* __restrict__ t1, const int* __restrict__ ei,
    const float* __restrict__ ew, __hip_bfloat162* __restrict__ agg1,
    int N, int E) {
  int gid = blockIdx.x * 256 + threadIdx.x;
  int e = gid >> 3;
  int p = gid & 7;
  if (e >= E) return;
  int s = ei[e];
  int d = ei[E + e];
  if ((unsigned)s >= (unsigned)N || (unsigned)d >= (unsigned)N) return;
  float w = ew[e];
  __hip_bfloat162 tv = t1[(size_t)s * F_P + p];
  __hip_bfloat162 v = __halves2bfloat162(
      __float2bfloat16(__bfloat162float(tv.x) * w),
      __float2bfloat16(__bfloat162float(tv.y) * w));
  unsafeAtomicAdd(&agg1[(size_t)d * F_P + p], v);
}

// ---------------------------------------------------------------------------
// K3: scatter layer2 in hidden space (W2 moved after aggregation):
//   agg2[dst] += relu(agg1[src] + b1) * w, packed-bf16 atomics.
// ---------------------------------------------------------------------------
__global__ __launch_bounds__(256) void scatter2_kernel(
    const __hip_bfloat162* __restrict__ agg1, const float* __restrict__ b1,
    const int* __restrict__ ei, const float* __restrict__ ew,
    __hip_bfloat162* __restrict__ agg2, int N, int E) {
  int gid = blockIdx.x * 256 + threadIdx.x;
  int e = gid >> 3;
  int p = gid & 7;
  if (e >= E) return;
  int s = ei[e];
  int d = ei[E + e];
  if ((unsigned)s >= (unsigned)N || (unsigned)d >= (unsigned)N) return;
  float w = ew[e];
  __hip_bfloat162 av = agg1[(size_t)s * F_P + p];
  float lo = __bfloat162float(av.x) + b1[2 * p];
  float hi = __bfloat162float(av.y) + b1[2 * p + 1];
  lo = lo > 0.f ? lo * w : 0.f;
  hi = hi > 0.f ? hi * w : 0.f;
  __hip_bfloat162 v = __halves2bfloat162(__float2bfloat16(lo), __float2bfloat16(hi));
  unsafeAtomicAdd(&agg2[(size_t)d * F_P + p], v);
}

// ---------------------------------------------------------------------------
// K4: fused epilogue — out[n] = log_softmax(agg2[n] @ W2 + b2)
// block = 320 threads, 8 nodes/block, thread = (local node, class)
// ---------------------------------------------------------------------------
__global__ __launch_bounds__(320) void gemm2_lsm_kernel(
    const __hip_bfloat162* __restrict__ agg2, const float* __restrict__ W2,
    const float* __restrict__ b2, float* __restrict__ out, int N) {
  __shared__ float w2lds[F_H * F_C];
  __shared__ float alds[8 * F_H];
  __shared__ float slds[8 * F_C];
  __shared__ float mlog[8];
  const int tid = threadIdx.x;
  const int nodeBase = blockIdx.x * 8;

  for (int i = tid; i < F_H * F_C; i += 320) w2lds[i] = W2[i];
  if (tid < 8 * F_P) {               // 64 threads load 64 bf16 pairs
    int node = nodeBase + (tid >> 3);
    __hip_bfloat162 v{};
    if (node < N) v = agg2[(size_t)nodeBase * F_P + tid];
    int r = tid >> 3, p = tid & 7;
    alds[r * F_H + 2 * p]     = __bfloat162float(v.x);
    alds[r * F_H + 2 * p + 1] = __bfloat162float(v.y);
  }
  __syncthreads();

  const int ln = tid / F_C;
  const int c = tid - ln * F_C;
  float acc = b2[c];
#pragma unroll
  for (int k = 0; k < F_H; ++k) acc = fmaf(alds[ln * F_H + k], w2lds[k * F_C + c], acc);
  slds[tid] = acc;
  __syncthreads();

  if (tid < 8) {
    const float* row = &slds[tid * F_C];
    float m = -INFINITY;
#pragma unroll
    for (int f = 0; f < F_C; ++f) m = fmaxf(m, row[f]);
    float s = 0.f;
#pragma unroll
    for (int f = 0; f < F_C; ++f) s += expf(row[f] - m);
    mlog[tid] = m + logf(s);
  }
  __syncthreads();

  const int node = nodeBase + ln;
  if (node < N) out[(size_t)nodeBase * F_C + tid] = slds[tid] - mlog[ln];
}

// ---------------------------------------------------------------------------
extern "C" void kernel_launch(void* const* d_in, const int* in_sizes, int n_in,
                              void* d_out, int out_size, void* d_ws, size_t ws_size,
                              hipStream_t stream) {
  const float* x  = (const float*)d_in[0];
  const int*   ei = (const int*)d_in[1];
  const float* ew = (const float*)d_in[2];
  const float* W1 = (const float*)d_in[3];
  const float* b1 = (const float*)d_in[4];
  const float* W2 = (const float*)d_in[5];
  const float* b2 = (const float*)d_in[6];
  float* out = (float*)d_out;

  const int N = in_sizes[0] / F_IN;
  const int E = in_sizes[2];

  // ws layout (bf16 pairs): t1[N*8] | agg1[N*8] | agg2[N*8]
  __hip_bfloat162* t1   = (__hip_bfloat162*)d_ws;
  __hip_bfloat162* agg1 = t1 + (size_t)N * F_P;
  __hip_bfloat162* agg2 = agg1 + (size_t)N * F_P;

  // zero agg1+agg2 in one contiguous memset (bf16 zero == 0x0000)
  hipMemsetAsync(agg1, 0, (size_t)N * F_P * 2 * sizeof(__hip_bfloat162), stream);

  gemm1_kernel<<<(N + 15) / 16, 256, 0, stream>>>(x, W1, t1, N);
  scatter1_kernel<<<((size_t)E * F_P + 255) / 256, 256, 0, stream>>>(t1, ei, ew, agg1, N, E);
  scatter2_kernel<<<((size_t)E * F_P + 255) / 256, 256, 0, stream>>>(agg1, b1, ei, ew, agg2, N, E);
  gemm2_lsm_kernel<<<(N + 7) / 8, 320, 0, stream>>>(agg2, W2, b2, out, N);
}

// Round 9
// 550.195 us; speedup vs baseline: 1.8738x; 1.0050x over previous
//
#include <hip/hip_runtime.h>
#include <hip/hip_bf16.h>
#include <cstdint>

#define F_IN 256
#define F_H  16
#define F_P  8    // bf16 pairs per hidden row
#define F_C  40
#define XS   32   // nodes per gemm1 block

// ---------------------------------------------------------------------------
// K1: t1[N,16] = x[N,256] @ W1[256,16], stored as bf16 PAIRS.
// 256 thr, 32 nodes/block, 2 outputs/thread. W1 transposed in LDS so both
// operands stream as ds_read_b128 (stride 260: f/f+8 2-way alias = free).
// ---------------------------------------------------------------------------
__global__ __launch_bounds__(256) void gemm1_kernel(
    const float* __restrict__ x, const float* __restrict__ W1,
    __hip_bfloat162* __restrict__ t1, int N) {
  __shared__ float xlds[XS * 260];     // 33.3 KB
  __shared__ float wlds[F_H * 260];    // 16.6 KB, transposed [f][k]
  const int tid = threadIdx.x;
  const int nodeBase = blockIdx.x * XS;

  // stage W1 transposed: global [k][f] -> lds [f][k]
  for (int i = tid; i < F_IN * F_H; i += 256) {
    int k = i >> 4, f = i & 15;
    wlds[f * 260 + k] = W1[i];
  }
  // stage x rows as float4 (coalesced)
  const float4* x4 = reinterpret_cast<const float4*>(x) + (size_t)nodeBase * (F_IN / 4);
  for (int i = tid; i < XS * (F_IN / 4); i += 256) {
    int r = i >> 6, c4 = i & 63;
    float4 v = make_float4(0.f, 0.f, 0.f, 0.f);
    if (nodeBase + r < N) v = x4[(size_t)r * (F_IN / 4) + c4];
    *reinterpret_cast<float4*>(&xlds[r * 260 + c4 * 4]) = v;
  }
  __syncthreads();

  const int r0 = tid >> 4;             // 0..15 (also handles r0+16)
  const int f  = tid & 15;
  const float4* xa = reinterpret_cast<const float4*>(&xlds[r0 * 260]);
  const float4* xb = reinterpret_cast<const float4*>(&xlds[(r0 + 16) * 260]);
  const float4* wf = reinterpret_cast<const float4*>(&wlds[f * 260]);
  float acca = 0.f, accb = 0.f;
#pragma unroll 8
  for (int k4 = 0; k4 < F_IN / 4; ++k4) {
    float4 w = wf[k4];
    float4 a = xa[k4];
    float4 b = xb[k4];
    acca = fmaf(a.x, w.x, acca); acca = fmaf(a.y, w.y, acca);
    acca = fmaf(a.z, w.z, acca); acca = fmaf(a.w, w.w, acca);
    accb = fmaf(b.x, w.x, accb); accb = fmaf(b.y, w.y, accb);
    accb = fmaf(b.z, w.z, accb); accb = fmaf(b.w, w.w, accb);
  }

  // pack adjacent features into bf16 pairs via shfl from odd lane
  float hia = __shfl_down(acca, 1);
  float hib = __shfl_down(accb, 1);
  if ((f & 1) == 0) {
    int p = f >> 1;
    if (nodeBase + r0 < N)
      t1[(size_t)(nodeBase + r0) * F_P + p] =
          __halves2bfloat162(__float2bfloat16(acca), __float2bfloat16(hia));
    if (nodeBase + r0 + 16 < N)
      t1[(size_t)(nodeBase + r0 + 16) * F_P + p] =
          __halves2bfloat162(__float2bfloat16(accb), __float2bfloat16(hib));
  }
}

// ---------------------------------------------------------------------------
// K2: scatter layer1 — agg1[dst] += t1[src] * w, packed-bf16 atomics.
// thread = (edge, pair); 8 consecutive threads share one edge.
// ---------------------------------------------------------------------------
__global__ __launch_bounds__(256) void scatter1_kernel(
    const __hip_bfloat162* __restrict__ t1, const int* __restrict__ ei,
    const float* __restrict__ ew, __hip_bfloat162* __restrict__ agg1,
    int N, int E) {
  int gid = blockIdx.x * 256 + threadIdx.x;
  int e = gid >> 3;
  int p = gid & 7;
  if (e >= E) return;
  int s = ei[e];
  int d = ei[E + e];
  if ((unsigned)s >= (unsigned)N || (unsigned)d >= (unsigned)N) return;
  float w = ew[e];
  __hip_bfloat162 tv = t1[(size_t)s * F_P + p];
  __hip_bfloat162 v = __halves2bfloat162(
      __float2bfloat16(__bfloat162float(tv.x) * w),
      __float2bfloat16(__bfloat162float(tv.y) * w));
  unsafeAtomicAdd(&agg1[(size_t)d * F_P + p], v);
}

// ---------------------------------------------------------------------------
// K3: scatter layer2 in hidden space (W2 moved after aggregation):
//   agg2[dst] += relu(agg1[src] + b1) * w, packed-bf16 atomics.
// ---------------------------------------------------------------------------
__global__ __launch_bounds__(256) void scatter2_kernel(
    const __hip_bfloat162* __restrict__ agg1, const float* __restrict__ b1,
    const int* __restrict__ ei, const float* __restrict__ ew,
    __hip_bfloat162* __restrict__ agg2, int N, int E) {
  int gid = blockIdx.x * 256 + threadIdx.x;
  int e = gid >> 3;
  int p = gid & 7;
  if (e >= E) return;
  int s = ei[e];
  int d = ei[E + e];
  if ((unsigned)s >= (unsigned)N || (unsigned)d >= (unsigned)N) return;
  float w = ew[e];
  __hip_bfloat162 av = agg1[(size_t)s * F_P + p];
  float lo = __bfloat162float(av.x) + b1[2 * p];
  float hi = __bfloat162float(av.y) + b1[2 * p + 1];
  lo = lo > 0.f ? lo * w : 0.f;
  hi = hi > 0.f ? hi * w : 0.f;
  __hip_bfloat162 v = __halves2bfloat162(__float2bfloat16(lo), __float2bfloat16(hi));
  unsafeAtomicAdd(&agg2[(size_t)d * F_P + p], v);
}

// ---------------------------------------------------------------------------
// K4: fused epilogue — out[n] = log_softmax(agg2[n] @ W2 + b2)
// block = 320 threads, 8 nodes/block, thread = (local node, class)
// ---------------------------------------------------------------------------
__global__ __launch_bounds__(320) void gemm2_lsm_kernel(
    const __hip_bfloat162* __restrict__ agg2, const float* __restrict__ W2,
    const float* __restrict__ b2, float* __restrict__ out, int N) {
  __shared__ float w2lds[F_H * F_C];
  __shared__ float alds[8 * F_H];
  __shared__ float slds[8 * F_C];
  __shared__ float mlog[8];
  const int tid = threadIdx.x;
  const int nodeBase = blockIdx.x * 8;

  for (int i = tid; i < F_H * F_C; i += 320) w2lds[i] = W2[i];
  if (tid < 8 * F_P) {               // 64 threads load 64 bf16 pairs
    int node = nodeBase + (tid >> 3);
    __hip_bfloat162 v{};
    if (node < N) v = agg2[(size_t)nodeBase * F_P + tid];
    int r = tid >> 3, p = tid & 7;
    alds[r * F_H + 2 * p]     = __bfloat162float(v.x);
    alds[r * F_H + 2 * p + 1] = __bfloat162float(v.y);
  }
  __syncthreads();

  const int ln = tid / F_C;
  const int c = tid - ln * F_C;
  float acc = b2[c];
#pragma unroll
  for (int k = 0; k < F_H; ++k) acc = fmaf(alds[ln * F_H + k], w2lds[k * F_C + c], acc);
  slds[tid] = acc;
  __syncthreads();

  if (tid < 8) {
    const float* row = &slds[tid * F_C];
    float m = -INFINITY;
#pragma unroll
    for (int f = 0; f < F_C; ++f) m = fmaxf(m, row[f]);
    float s = 0.f;
#pragma unroll
    for (int f = 0; f < F_C; ++f) s += expf(row[f] - m);
    mlog[tid] = m + logf(s);
  }
  __syncthreads();

  const int node = nodeBase + ln;
  if (node < N) out[(size_t)nodeBase * F_C + tid] = slds[tid] - mlog[ln];
}

// ---------------------------------------------------------------------------
extern "C" void kernel_launch(void* const* d_in, const int* in_sizes, int n_in,
                              void* d_out, int out_size, void* d_ws, size_t ws_size,
                              hipStream_t stream) {
  const float* x  = (const float*)d_in[0];
  const int*   ei = (const int*)d_in[1];
  const float* ew = (const float*)d_in[2];
  const float* W1 = (const float*)d_in[3];
  const float* b1 = (const float*)d_in[4];
  const float* W2 = (const float*)d_in[5];
  const float* b2 = (const float*)d_in[6];
  float* out = (float*)d_out;

  const int N = in_sizes[0] / F_IN;
  const int E = in_sizes[2];

  // ws layout (bf16 pairs): t1[N*8] | agg1[N*8] | agg2[N*8]
  __hip_bfloat162* t1   = (__hip_bfloat162*)d_ws;
  __hip_bfloat162* agg1 = t1 + (size_t)N * F_P;
  __hip_bfloat162* agg2 = agg1 + (size_t)N * F_P;

  hipMemsetAsync(agg1, 0, (size_t)N * F_P * 2 * sizeof(__hip_bfloat162), stream);

  gemm1_kernel<<<(N + XS - 1) / XS, 256, 0, stream>>>(x, W1, t1, N);
  scatter1_kernel<<<((size_t)E * F_P + 255) / 256, 256, 0, stream>>>(t1, ei, ew, agg1, N, E);
  scatter2_kernel<<<((size_t)E * F_P + 255) / 256, 256, 0, stream>>>(agg1, b1, ei, ew, agg2, N, E);
  gemm2_lsm_kernel<<<(N + 7) / 8, 320, 0, stream>>>(agg2, W2, b2, out, N);
}

// Round 12
// 532.855 us; speedup vs baseline: 1.9348x; 1.0325x over previous
//
#include <hip/hip_runtime.h>
#include <hip/hip_bf16.h>
#include <cstdint>

#define F_IN 256
#define F_H  16
#define F_P  8    // bf16 pairs per hidden row
#define F_C  40
#define XS   32   // nodes per gemm1 / lsm block

// ---------------------------------------------------------------------------
// K1: t1[N,16] = x[N,256] @ W1[256,16] (bf16 pairs) + zero agg1/agg2 slices.
// 256 thr, 32 nodes/block, 2 outputs/thread, all-LDS reads as ds_read_b128.
// ---------------------------------------------------------------------------
__global__ __launch_bounds__(256) void gemm1_kernel(
    const float* __restrict__ x, const float* __restrict__ W1,
    __hip_bfloat162* __restrict__ t1,
    unsigned* __restrict__ agg1z, unsigned* __restrict__ agg2z, int N) {
  __shared__ float xlds[XS * 260];     // 33.3 KB
  __shared__ float wlds[F_H * 260];    // 16.6 KB, transposed [f][k]
  const int tid = threadIdx.x;
  const int nodeBase = blockIdx.x * XS;

  // zero this block's slice of agg1+agg2 (replaces the memset dispatch)
  {
    int lim = min(XS, N - nodeBase) * F_P;       // normally 256
    size_t base = (size_t)nodeBase * F_P;
    if (tid < lim) { agg1z[base + tid] = 0u; agg2z[base + tid] = 0u; }
  }

  // stage W1 transposed: global [k][f] -> lds [f][k]
  for (int i = tid; i < F_IN * F_H; i += 256) {
    int k = i >> 4, f = i & 15;
    wlds[f * 260 + k] = W1[i];
  }
  // stage x rows as float4 (coalesced)
  const float4* x4 = reinterpret_cast<const float4*>(x) + (size_t)nodeBase * (F_IN / 4);
  for (int i = tid; i < XS * (F_IN / 4); i += 256) {
    int r = i >> 6, c4 = i & 63;
    float4 v = make_float4(0.f, 0.f, 0.f, 0.f);
    if (nodeBase + r < N) v = x4[(size_t)r * (F_IN / 4) + c4];
    *reinterpret_cast<float4*>(&xlds[r * 260 + c4 * 4]) = v;
  }
  __syncthreads();

  const int r0 = tid >> 4;             // 0..15 (also handles r0+16)
  const int f  = tid & 15;
  const float4* xa = reinterpret_cast<const float4*>(&xlds[r0 * 260]);
  const float4* xb = reinterpret_cast<const float4*>(&xlds[(r0 + 16) * 260]);
  const float4* wf = reinterpret_cast<const float4*>(&wlds[f * 260]);
  float acca = 0.f, accb = 0.f;
#pragma unroll 8
  for (int k4 = 0; k4 < F_IN / 4; ++k4) {
    float4 w = wf[k4];
    float4 a = xa[k4];
    float4 b = xb[k4];
    acca = fmaf(a.x, w.x, acca); acca = fmaf(a.y, w.y, acca);
    acca = fmaf(a.z, w.z, acca); acca = fmaf(a.w, w.w, acca);
    accb = fmaf(b.x, w.x, accb); accb = fmaf(b.y, w.y, accb);
    accb = fmaf(b.z, w.z, accb); accb = fmaf(b.w, w.w, accb);
  }

  float hia = __shfl_down(acca, 1);
  float hib = __shfl_down(accb, 1);
  if ((f & 1) == 0) {
    int p = f >> 1;
    if (nodeBase + r0 < N)
      t1[(size_t)(nodeBase + r0) * F_P + p] =
          __halves2bfloat162(__float2bfloat16(acca), __float2bfloat16(hia));
    if (nodeBase + r0 + 16 < N)
      t1[(size_t)(nodeBase + r0 + 16) * F_P + p] =
          __halves2bfloat162(__float2bfloat16(accb), __float2bfloat16(hib));
  }
}

// ---------------------------------------------------------------------------
// K2: scatter layer1 — agg1[dst] += t1[src]*w. ILP=2: thread = (2 edges, pair)
// ---------------------------------------------------------------------------
__global__ __launch_bounds__(256) void scatter1_kernel(
    const __hip_bfloat162* __restrict__ t1, const int* __restrict__ ei,
    const float* __restrict__ ew, __hip_bfloat162* __restrict__ agg1,
    int N, int E) {
  int gid = blockIdx.x * 256 + threadIdx.x;
  int p = gid & 7;
  int e0 = (gid >> 3) << 1;
  if (e0 >= E) return;
  int e1 = e0 + 1;
  bool ok1 = (e1 < E);

  int s0 = ei[e0], d0 = ei[E + e0];
  int s1 = ok1 ? ei[e1] : s0;
  int d1 = ok1 ? ei[E + e1] : d0;
  float w0 = ew[e0];
  float w1 = ok1 ? ew[e1] : 0.f;

  bool v0 = ((unsigned)s0 < (unsigned)N) && ((unsigned)d0 < (unsigned)N);
  bool v1 = ok1 && ((unsigned)s1 < (unsigned)N) && ((unsigned)d1 < (unsigned)N);
  __hip_bfloat162 t0 = t1[(size_t)(v0 ? s0 : 0) * F_P + p];
  __hip_bfloat162 t1v = t1[(size_t)(v1 ? s1 : 0) * F_P + p];

  if (v0) {
    __hip_bfloat162 a = __halves2bfloat162(
        __float2bfloat16(__bfloat162float(t0.x) * w0),
        __float2bfloat16(__bfloat162float(t0.y) * w0));
    unsafeAtomicAdd(&agg1[(size_t)d0 * F_P + p], a);
  }
  if (v1) {
    __hip_bfloat162 a = __halves2bfloat162(
        __float2bfloat16(__bfloat162float(t1v.x) * w1),
        __float2bfloat16(__bfloat162float(t1v.y) * w1));
    unsafeAtomicAdd(&agg1[(size_t)d1 * F_P + p], a);
  }
}

// ---------------------------------------------------------------------------
// K3: scatter layer2 in hidden space — agg2[dst] += relu(agg1[src]+b1)*w.
// ILP=2 as above.
// ---------------------------------------------------------------------------
__global__ __launch_bounds__(256) void scatter2_kernel(
    const __hip_bfloat162* __restrict__ agg1, const float* __restrict__ b1,
    const int* __restrict__ ei, const float* __restrict__ ew,
    __hip_bfloat162* __restrict__ agg2, int N, int E) {
  int gid = blockIdx.x * 256 + threadIdx.x;
  int p = gid & 7;
  int e0 = (gid >> 3) << 1;
  if (e0 >= E) return;
  int e1 = e0 + 1;
  bool ok1 = (e1 < E);

  float2 bb = reinterpret_cast<const float2*>(b1)[p];
  int s0 = ei[e0], d0 = ei[E + e0];
  int s1 = ok1 ? ei[e1] : s0;
  int d1 = ok1 ? ei[E + e1] : d0;
  float w0 = ew[e0];
  float w1 = ok1 ? ew[e1] : 0.f;

  bool v0 = ((unsigned)s0 < (unsigned)N) && ((unsigned)d0 < (unsigned)N);
  bool v1 = ok1 && ((unsigned)s1 < (unsigned)N) && ((unsigned)d1 < (unsigned)N);
  __hip_bfloat162 a0 = agg1[(size_t)(v0 ? s0 : 0) * F_P + p];
  __hip_bfloat162 a1 = agg1[(size_t)(v1 ? s1 : 0) * F_P + p];

  if (v0) {
    float lo = fmaxf(__bfloat162float(a0.x) + bb.x, 0.f) * w0;
    float hi = fmaxf(__bfloat162float(a0.y) + bb.y, 0.f) * w0;
    unsafeAtomicAdd(&agg2[(size_t)d0 * F_P + p],
                    __halves2bfloat162(__float2bfloat16(lo), __float2bfloat16(hi)));
  }
  if (v1) {
    float lo = fmaxf(__bfloat162float(a1.x) + bb.x, 0.f) * w1;
    float hi = fmaxf(__bfloat162float(a1.y) + bb.y, 0.f) * w1;
    unsafeAtomicAdd(&agg2[(size_t)d1 * F_P + p],
                    __halves2bfloat162(__float2bfloat16(lo), __float2bfloat16(hi)));
  }
}

// ---------------------------------------------------------------------------
// K4: fused epilogue — out[n] = log_softmax(agg2[n] @ W2 + b2)
// 256 thr, 32 nodes/block; 8 lanes per row, 5 classes per lane.
// Wave-parallel max/sum via __shfl_xor width 8 (no serial phase).
// ---------------------------------------------------------------------------
__global__ __launch_bounds__(256) void gemm2_lsm_kernel(
    const __hip_bfloat162* __restrict__ agg2, const float* __restrict__ W2,
    const float* __restrict__ b2, float* __restrict__ out, int N) {
  __shared__ float w2lds[F_H * F_C];   // [k][c]
  __shared__ float b2lds[F_C];
  __shared__ float alds[XS * F_H];
  const int tid = threadIdx.x;
  const int nodeBase = blockIdx.x * XS;

  for (int i = tid; i < F_H * F_C; i += 256) w2lds[i] = W2[i];
  if (tid < F_C) b2lds[tid] = b2[tid];
  {
    int node = nodeBase + (tid >> 3);
    __hip_bfloat162 v = __halves2bfloat162(__float2bfloat16(0.f), __float2bfloat16(0.f));
    if (node < N) v = agg2[(size_t)node * F_P + (tid & 7)];
    alds[(tid >> 3) * F_H + 2 * (tid & 7)]     = __bfloat162float(v.x);
    alds[(tid >> 3) * F_H + 2 * (tid & 7) + 1] = __bfloat162float(v.y);
  }
  __syncthreads();

  const int r = tid >> 3;              // local row
  const int l = tid & 7;               // lane in 8-group
  const int node = nodeBase + r;
  const float* arow = &alds[r * F_H];

  float acc[5];
#pragma unroll
  for (int j = 0; j < 5; ++j) {
    int c = l * 5 + j;
    float a = b2lds[c];
#pragma unroll
    for (int k = 0; k < F_H; ++k) a = fmaf(arow[k], w2lds[k * F_C + c], a);
    acc[j] = a;
  }

  float m = acc[0];
#pragma unroll
  for (int j = 1; j < 5; ++j) m = fmaxf(m, acc[j]);
#pragma unroll
  for (int off = 1; off < 8; off <<= 1) m = fmaxf(m, __shfl_xor(m, off, 8));

  float s = 0.f;
#pragma unroll
  for (int j = 0; j < 5; ++j) s += __expf(acc[j] - m);
#pragma unroll
  for (int off = 1; off < 8; off <<= 1) s += __shfl_xor(s, off, 8);

  float ml = m + __logf(s);
  if (node < N) {
#pragma unroll
    for (int j = 0; j < 5; ++j)
      out[(size_t)node * F_C + l * 5 + j] = acc[j] - ml;
  }
}

// ---------------------------------------------------------------------------
extern "C" void kernel_launch(void* const* d_in, const int* in_sizes, int n_in,
                              void* d_out, int out_size, void* d_ws, size_t ws_size,
                              hipStream_t stream) {
  const float* x  = (const float*)d_in[0];
  const int*   ei = (const int*)d_in[1];
  const float* ew = (const float*)d_in[2];
  const float* W1 = (const float*)d_in[3];
  const float* b1 = (const float*)d_in[4];
  const float* W2 = (const float*)d_in[5];
  const float* b2 = (const float*)d_in[6];
  float* out = (float*)d_out;

  const int N = in_sizes[0] / F_IN;
  const int E = in_sizes[2];

  // ws layout (bf16 pairs): t1[N*8] | agg1[N*8] | agg2[N*8]  (contiguous)
  __hip_bfloat162* t1   = (__hip_bfloat162*)d_ws;
  __hip_bfloat162* agg1 = t1 + (size_t)N * F_P;
  __hip_bfloat162* agg2 = agg1 + (size_t)N * F_P;

  gemm1_kernel<<<(N + XS - 1) / XS, 256, 0, stream>>>(
      x, W1, t1, (unsigned*)agg1, (unsigned*)agg2, N);
  scatter1_kernel<<<((size_t)E * 4 + 255) / 256, 256, 0, stream>>>(t1, ei, ew, agg1, N, E);
  scatter2_kernel<<<((size_t)E * 4 + 255) / 256, 256, 0, stream>>>(agg1, b1, ei, ew, agg2, N, E);
  gemm2_lsm_kernel<<<(N + XS - 1) / XS, 256, 0, stream>>>(agg2, W2, b2, out, N);
}